// Round 1
// baseline (236.196 us; speedup 1.0000x reference)
//
#include <hip/hip_runtime.h>

// Problem constants (from reference)
#define IN_FEAT    128
#define EDGE_EMBED 32
// W1_w: [256, 256] row-major (out k, in f). W2_w: [2, 288] row-major.

// ---------------------------------------------------------------------------
// Kernel 1: collapse the two linear layers (no nonlinearity between them!)
//   M[f,j]  = sum_k W1_w[k,f] * W2_w[j,k]        (f in 0..255, j in 0..1)
//   bias[j] = sum_k W1_b[k]   * W2_w[j,k] + W2_b[j]
// ws layout (floats): ws[f*2+j] = M[f,j] for f<256;  ws[512+j] = bias[j]
// ---------------------------------------------------------------------------
__global__ __launch_bounds__(256) void precompute_kernel(
    const float* __restrict__ W1_w, const float* __restrict__ W1_b,
    const float* __restrict__ W2_w, const float* __restrict__ W2_b,
    float* __restrict__ ws) {
    const int f = threadIdx.x;  // 0..255
    float m0 = 0.f, m1 = 0.f;
#pragma unroll 8
    for (int k = 0; k < 256; ++k) {
        const float w1 = W1_w[k * 256 + f];   // coalesced across f
        m0 = fmaf(w1, W2_w[k], m0);           // j=0 row of W2_w
        m1 = fmaf(w1, W2_w[288 + k], m1);     // j=1 row of W2_w
    }
    ws[f * 2 + 0] = m0;
    ws[f * 2 + 1] = m1;
    if (f < 2) {
        float b = W2_b[f];
        for (int k = 0; k < 256; ++k) b = fmaf(W1_b[k], W2_w[f * 288 + k], b);
        ws[512 + f] = b;
    }
}

// ---------------------------------------------------------------------------
// Kernel 2: per-edge fused gather + collapsed affine map.
// 32 lanes per edge: lane p loads h_u[p*4..p*4+3] (float4 -> one 512B row per
// instruction, fully coalesced), same for h_v, plus e[edge*32+p].
// Weights register-resident (18 floats/lane, loaded once per block).
// 5-step shfl_xor reduction (masks 16..1 stay within 32-lane halves of wave64).
// ---------------------------------------------------------------------------
__global__ __launch_bounds__(256, 8) void edge_score_kernel(
    const float* __restrict__ h, const int* __restrict__ src,
    const int* __restrict__ dst, const float* __restrict__ e,
    const float* __restrict__ W2_w, const float* __restrict__ ws,
    float* __restrict__ out, int E, int numGroups) {
    const int p = threadIdx.x & 31;                      // lane within 32-lane group
    int group = blockIdx.x * (blockDim.x >> 5) + (threadIdx.x >> 5);

    // Register-resident collapsed weights for this lane's 4 features.
    // ws[f*2+j]: lane p owns f = p*4 .. p*4+3 (for h_u) and 128+p*4.. (for h_v)
    const float4 muA = *(const float4*)(ws + p * 8);         // M[4p..4p+1][0..1]
    const float4 muB = *(const float4*)(ws + p * 8 + 4);     // M[4p+2..4p+3][0..1]
    const float4 mvA = *(const float4*)(ws + 256 + p * 8);
    const float4 mvB = *(const float4*)(ws + 256 + p * 8 + 4);
    const float w2e0 = W2_w[256 + p];                        // e-part of W2, row 0
    const float w2e1 = W2_w[288 + 256 + p];                  // row 1
    const float b0 = ws[512], b1 = ws[513];

    for (int edge = group; edge < E; edge += numGroups) {
        const int s = src[edge];
        const int d = dst[edge];
        const float4 hu = *(const float4*)(h + (size_t)s * IN_FEAT + p * 4);
        const float4 hv = *(const float4*)(h + (size_t)d * IN_FEAT + p * 4);
        const float  ev = e[(size_t)edge * EDGE_EMBED + p];

        float acc0 = ev * w2e0;
        float acc1 = ev * w2e1;
        acc0 = fmaf(hu.x, muA.x, acc0); acc1 = fmaf(hu.x, muA.y, acc1);
        acc0 = fmaf(hu.y, muA.z, acc0); acc1 = fmaf(hu.y, muA.w, acc1);
        acc0 = fmaf(hu.z, muB.x, acc0); acc1 = fmaf(hu.z, muB.y, acc1);
        acc0 = fmaf(hu.w, muB.z, acc0); acc1 = fmaf(hu.w, muB.w, acc1);
        acc0 = fmaf(hv.x, mvA.x, acc0); acc1 = fmaf(hv.x, mvA.y, acc1);
        acc0 = fmaf(hv.y, mvA.z, acc0); acc1 = fmaf(hv.y, mvA.w, acc1);
        acc0 = fmaf(hv.z, mvB.x, acc0); acc1 = fmaf(hv.z, mvB.y, acc1);
        acc0 = fmaf(hv.w, mvB.z, acc0); acc1 = fmaf(hv.w, mvB.w, acc1);

        // Reduce across the 32-lane group (xor masks < 32 never cross halves)
        #pragma unroll
        for (int m = 16; m >= 1; m >>= 1) {
            acc0 += __shfl_xor(acc0, m);
            acc1 += __shfl_xor(acc1, m);
        }
        if (p == 0) {
            float2 r; r.x = acc0 + b0; r.y = acc1 + b1;
            *(float2*)(out + (size_t)edge * 2) = r;
        }
    }
}

extern "C" void kernel_launch(void* const* d_in, const int* in_sizes, int n_in,
                              void* d_out, int out_size, void* d_ws, size_t ws_size,
                              hipStream_t stream) {
    const float* h    = (const float*)d_in[0];
    const int*   src  = (const int*)d_in[1];
    const int*   dst  = (const int*)d_in[2];
    const float* e    = (const float*)d_in[3];
    const float* W1_w = (const float*)d_in[4];
    const float* W1_b = (const float*)d_in[5];
    const float* W2_w = (const float*)d_in[6];
    const float* W2_b = (const float*)d_in[7];
    float* out = (float*)d_out;
    float* ws  = (float*)d_ws;

    const int E = in_sizes[1];  // 640000 edges

    precompute_kernel<<<1, 256, 0, stream>>>(W1_w, W1_b, W2_w, W2_b, ws);

    const int BLOCKS = 2048;                 // persistent-ish grid-stride
    const int numGroups = BLOCKS * (256 / 32);
    edge_score_kernel<<<BLOCKS, 256, 0, stream>>>(h, src, dst, e, W2_w, ws,
                                                  out, E, numGroups);
}

// Round 2
// 171.824 us; speedup vs baseline: 1.3746x; 1.3746x over previous
//
#include <hip/hip_runtime.h>

#define IN_FEAT    128
#define EDGE_EMBED 32
// W1_w: [256, 256] row-major. W2_w: [2, 288] row-major.
//
// Factorization (no nonlinearity anywhere):
//   score[i,j] = pu[src[i]][j] + pv[dst[i]][j] + sum_m e[i,m]*W2_w[j,256+m] + bias[j]
//   pu[n][j] = sum_{f<128} h[n,f]   * M[f,j]
//   pv[n][j] = sum_{f<128} h[n,f]   * M[128+f,j]
//   M[f,j]   = sum_k W1_w[k,f] * W2_w[j,k]
//   bias[j]  = sum_k W1_b[k]   * W2_w[j,k] + W2_b[j]
//
// ws layout (floats):
//   [0..511]      M[f*2+j]
//   [512..513]    bias
//   [1024 ..]     pu[n*2+j]   (N*2 floats)
//   [1024+2N ..]  pv[n*2+j]   (N*2 floats)    total < 1 MB

// ---------------------------------------------------------------------------
// Kernel A: collapse W1/W2 into M + bias. Bias via wave-wide shuffle reduce
// (R1's 2-thread serial loop was ~tens of µs of hidden latency).
// ---------------------------------------------------------------------------
__global__ __launch_bounds__(256) void precompute_kernel(
    const float* __restrict__ W1_w, const float* __restrict__ W1_b,
    const float* __restrict__ W2_w, const float* __restrict__ W2_b,
    float* __restrict__ ws) {
    const int f = threadIdx.x;  // 0..255
    float m0 = 0.f, m1 = 0.f;
#pragma unroll 16
    for (int k = 0; k < 256; ++k) {
        const float w1 = W1_w[k * 256 + f];   // coalesced across f
        m0 = fmaf(w1, W2_w[k], m0);
        m1 = fmaf(w1, W2_w[288 + k], m1);
    }
    ws[f * 2 + 0] = m0;
    ws[f * 2 + 1] = m1;

    // bias: first wave only, 4 elements/lane then 64-lane butterfly
    if (threadIdx.x < 64) {
        const int t = threadIdx.x;
        float b0 = 0.f, b1 = 0.f;
#pragma unroll
        for (int m = 0; m < 4; ++m) {
            const int k = t + 64 * m;
            const float wb = W1_b[k];
            b0 = fmaf(wb, W2_w[k], b0);
            b1 = fmaf(wb, W2_w[288 + k], b1);
        }
#pragma unroll
        for (int m = 32; m >= 1; m >>= 1) {
            b0 += __shfl_xor(b0, m);
            b1 += __shfl_xor(b1, m);
        }
        if (t == 0) {
            ws[512] = b0 + W2_b[0];
            ws[513] = b1 + W2_b[1];
        }
    }
}

// ---------------------------------------------------------------------------
// Kernel B: per-node projections. 32 lanes per node row (one float4/lane
// covers the 512 B row in one coalesced instruction); 4 accumulators;
// 5-step shuffle reduce (masks <=16 stay inside each 32-lane half).
// Reads h exactly once: 25.6 MB -> ~5 us.
// ---------------------------------------------------------------------------
__global__ __launch_bounds__(256, 8) void node_proj_kernel(
    const float* __restrict__ h, const float* __restrict__ ws,
    float* __restrict__ pu, float* __restrict__ pv, int N) {
    const int p = threadIdx.x & 31;
    const int node = blockIdx.x * 8 + (threadIdx.x >> 5);
    if (node >= N) return;

    const float4 muA = *(const float4*)(ws + p * 8);
    const float4 muB = *(const float4*)(ws + p * 8 + 4);
    const float4 mvA = *(const float4*)(ws + 256 + p * 8);
    const float4 mvB = *(const float4*)(ws + 256 + p * 8 + 4);

    const float4 hr = *(const float4*)(h + (size_t)node * IN_FEAT + p * 4);

    float u0 = hr.x * muA.x, u1 = hr.x * muA.y;
    u0 = fmaf(hr.y, muA.z, u0); u1 = fmaf(hr.y, muA.w, u1);
    u0 = fmaf(hr.z, muB.x, u0); u1 = fmaf(hr.z, muB.y, u1);
    u0 = fmaf(hr.w, muB.z, u0); u1 = fmaf(hr.w, muB.w, u1);
    float v0 = hr.x * mvA.x, v1 = hr.x * mvA.y;
    v0 = fmaf(hr.y, mvA.z, v0); v1 = fmaf(hr.y, mvA.w, v1);
    v0 = fmaf(hr.z, mvB.x, v0); v1 = fmaf(hr.z, mvB.y, v1);
    v0 = fmaf(hr.w, mvB.z, v0); v1 = fmaf(hr.w, mvB.w, v1);

#pragma unroll
    for (int m = 16; m >= 1; m >>= 1) {
        u0 += __shfl_xor(u0, m); u1 += __shfl_xor(u1, m);
        v0 += __shfl_xor(v0, m); v1 += __shfl_xor(v1, m);
    }
    if (p == 0) {
        *(float2*)(pu + (size_t)node * 2) = make_float2(u0, u1);
        *(float2*)(pv + (size_t)node * 2) = make_float2(v0, v1);
    }
}

// ---------------------------------------------------------------------------
// Kernel C: edge scores. 8 lanes per edge: lane p covers e[edge*32+p*4..+3]
// (one float4; 8-lane group = 128 B contiguous, wave = 1 KB contiguous).
// Lane 0 gathers pu[src] (8 B), lane 4 gathers pv[dst] — both tables are
// 400 KB, L2-resident on every XCD. 3-step shuffle reduce over 8 lanes.
// ---------------------------------------------------------------------------
__global__ __launch_bounds__(256, 8) void edge_score_kernel(
    const int* __restrict__ src, const int* __restrict__ dst,
    const float* __restrict__ e, const float* __restrict__ W2_w,
    const float* __restrict__ ws, const float* __restrict__ pu,
    const float* __restrict__ pv, float* __restrict__ out,
    int E, int numGroups) {
    const int p = threadIdx.x & 7;
    int group = blockIdx.x * (blockDim.x >> 3) + (threadIdx.x >> 3);

    // e-part weights for this lane's 4 embed dims
    const float4 w0 = *(const float4*)(W2_w + 256 + p * 4);        // j=0
    const float4 w1 = *(const float4*)(W2_w + 544 + p * 4);        // j=1
    const float b0 = ws[512], b1 = ws[513];

    for (int edge = group; edge < E; edge += numGroups) {
        const float4 ev = *(const float4*)(e + (size_t)edge * EDGE_EMBED + p * 4);

        float acc0 = ev.x * w0.x;
        float acc1 = ev.x * w1.x;
        acc0 = fmaf(ev.y, w0.y, acc0); acc1 = fmaf(ev.y, w1.y, acc1);
        acc0 = fmaf(ev.z, w0.z, acc0); acc1 = fmaf(ev.z, w1.z, acc1);
        acc0 = fmaf(ev.w, w0.w, acc0); acc1 = fmaf(ev.w, w1.w, acc1);

        if (p == 0) {                       // src endpoint projection
            const int s = src[edge];
            const float2 u = *(const float2*)(pu + (size_t)s * 2);
            acc0 += u.x; acc1 += u.y;
        } else if (p == 4) {                // dst endpoint projection
            const int d = dst[edge];
            const float2 v = *(const float2*)(pv + (size_t)d * 2);
            acc0 += v.x; acc1 += v.y;
        }

#pragma unroll
        for (int m = 4; m >= 1; m >>= 1) {  // masks 4,2,1: stay in 8-lane group
            acc0 += __shfl_xor(acc0, m);
            acc1 += __shfl_xor(acc1, m);
        }
        if (p == 0) {
            *(float2*)(out + (size_t)edge * 2) = make_float2(acc0 + b0, acc1 + b1);
        }
    }
}

extern "C" void kernel_launch(void* const* d_in, const int* in_sizes, int n_in,
                              void* d_out, int out_size, void* d_ws, size_t ws_size,
                              hipStream_t stream) {
    const float* h    = (const float*)d_in[0];
    const int*   src  = (const int*)d_in[1];
    const int*   dst  = (const int*)d_in[2];
    const float* e    = (const float*)d_in[3];
    const float* W1_w = (const float*)d_in[4];
    const float* W1_b = (const float*)d_in[5];
    const float* W2_w = (const float*)d_in[6];
    const float* W2_b = (const float*)d_in[7];
    float* out = (float*)d_out;
    float* ws  = (float*)d_ws;

    const int E = in_sizes[1];
    const int N = in_sizes[0] / IN_FEAT;

    float* pu = ws + 1024;
    float* pv = ws + 1024 + (size_t)N * 2;

    precompute_kernel<<<1, 256, 0, stream>>>(W1_w, W1_b, W2_w, W2_b, ws);
    node_proj_kernel<<<(N + 7) / 8, 256, 0, stream>>>(h, ws, pu, pv, N);

    const int BLOCKS = 2048;               // 8 blocks/CU resident
    const int numGroups = BLOCKS * (256 / 8);
    edge_score_kernel<<<BLOCKS, 256, 0, stream>>>(src, dst, e, W2_w, ws, pu, pv,
                                                  out, E, numGroups);
}